// Round 1
// baseline (153.314 us; speedup 1.0000x reference)
//
#include <hip/hip_runtime.h>

#define BATCH 128
#define CH    768
#define HW    576      // 24*24
#define NTOK  144      // 12*12 tokens
#define NMERGE 72
#define NKEEP 360      // 72*1 + 72*4 output tokens
#define CCH   96       // channels per score block
#define NCH   8        // channel chunks (768/96)

// ---------------------------------------------------------------------------
// Kernel 1: per-(b, channel-chunk) partial scores.
// score_partial[b][ch][t] = sum_{c in chunk} |x01-a|+|x10-a|+|x11-a|
// Deterministic fixed-order summation (no atomics).
// ---------------------------------------------------------------------------
__global__ __launch_bounds__(256) void score_kernel(const float* __restrict__ x,
                                                    float* __restrict__ part) {
    int b  = blockIdx.x >> 3;
    int ch = blockIdx.x & 7;
    __shared__ __align__(16) float img[HW];
    int tid = threadIdx.x;
    float acc = 0.f;
    int i = tid / 12, j = tid % 12;          // token coords (valid for tid<144)
    int p00 = (2 * i) * 24 + 2 * j;
    const float4* xb = (const float4*)(x + ((size_t)b * CH + (size_t)ch * CCH) * HW);
    for (int cc = 0; cc < CCH; ++cc) {
        if (tid < 144) ((float4*)img)[tid] = xb[cc * 144 + tid];
        __syncthreads();
        if (tid < 144) {
            float a = img[p00];
            acc += fabsf(img[p00 + 1] - a)
                 + fabsf(img[p00 + 24] - a)
                 + fabsf(img[p00 + 25] - a);
        }
        __syncthreads();
    }
    if (tid < 144) part[(size_t)blockIdx.x * NTOK + tid] = acc;
}

// ---------------------------------------------------------------------------
// Kernel 2: per-batch. Reduce partials -> scores, rank (stable), build the
// per-pixel include mask, prefix-sum via ballot/popcount, emit token_idx
// (float into d_out tail, int into ws for the gather).
// 576 threads = 9 waves: thread == pixel index.
// ---------------------------------------------------------------------------
__global__ __launch_bounds__(576) void select_kernel(const float* __restrict__ part,
                                                     float* __restrict__ tok_f,
                                                     int* __restrict__ tok_i) {
    int b = blockIdx.x;
    int tid = threadIdx.x;
    __shared__ float s[NTOK];
    __shared__ int   merged[NTOK];
    __shared__ unsigned long long wmask[9];

    if (tid < NTOK) {
        float v = 0.f;
        for (int ch = 0; ch < NCH; ++ch)
            v += part[((size_t)b * NCH + ch) * NTOK + tid];
        s[tid] = v;
    }
    __syncthreads();
    if (tid < NTOK) {
        float v = s[tid];
        int rank = 0;
        for (int u = 0; u < NTOK; ++u) {
            float su = s[u];
            rank += (su < v) || (su == v && u < tid);   // stable argsort rank
        }
        merged[tid] = (rank < NMERGE);
    }
    __syncthreads();

    // tid = pixel p in [0,576)
    int row = tid / 24, col = tid % 24;
    int t = (row >> 1) * 12 + (col >> 1);
    bool inc = merged[t] ? ((row & 1) == 0 && (col & 1) == 0) : true;
    unsigned long long mask = __ballot(inc);
    int wv = tid >> 6, lane = tid & 63;
    if (lane == 0) wmask[wv] = mask;
    __syncthreads();
    int pos = 0;
    for (int w = 0; w < wv; ++w) pos += __popcll(wmask[w]);
    pos += __popcll(mask & ((1ULL << lane) - 1ULL));
    if (inc) {
        tok_f[(size_t)b * NKEEP + pos] = (float)tid;  // output 1 (as float)
        tok_i[(size_t)b * NKEEP + pos] = tid;         // for gather kernel
    }
}

// ---------------------------------------------------------------------------
// Kernel 3: gather + transpose. out[b,k,c] = x[b,c,tok[b,k]].
// Tile 64 tokens x 64 channels via LDS (padded, conflict-free both phases).
// Reads coalesce along the (sorted, dense) token axis; writes coalesce along c.
// ---------------------------------------------------------------------------
__global__ __launch_bounds__(256) void gather_kernel(const float* __restrict__ x,
                                                     const int* __restrict__ tok_i,
                                                     float* __restrict__ out) {
    __shared__ float lds[64][65];
    int b = blockIdx.z, kt = blockIdx.y, ct = blockIdx.x;
    int tid = threadIdx.x, lane = tid & 63, wv = tid >> 6;
    int k = kt * 64 + lane;
    bool kvalid = (k < NKEEP);
    int p = kvalid ? tok_i[(size_t)b * NKEEP + k] : 0;
    const float* xb = x + ((size_t)b * CH + (size_t)ct * 64) * HW;
    for (int cc = wv; cc < 64; cc += 4)
        lds[cc][lane] = kvalid ? xb[(size_t)cc * HW + p] : 0.f;
    __syncthreads();
    float* ob = out + ((size_t)b * NKEEP + (size_t)kt * 64) * CH + (size_t)ct * 64;
    for (int kk = wv; kk < 64; kk += 4)
        if (kt * 64 + kk < NKEEP) ob[(size_t)kk * CH + lane] = lds[lane][kk];
}

extern "C" void kernel_launch(void* const* d_in, const int* in_sizes, int n_in,
                              void* d_out, int out_size, void* d_ws, size_t ws_size,
                              hipStream_t stream) {
    const float* x = (const float*)d_in[0];
    float* outf = (float*)d_out;
    float* part = (float*)d_ws;                                   // 128*8*144 f32
    int* tok_i = (int*)((char*)d_ws + (size_t)BATCH * NCH * NTOK * sizeof(float));
    float* tok_f = outf + (size_t)BATCH * NKEEP * CH;             // token_idx area

    score_kernel<<<dim3(BATCH * NCH), 256, 0, stream>>>(x, part);
    select_kernel<<<dim3(BATCH), 576, 0, stream>>>(part, tok_f, tok_i);
    gather_kernel<<<dim3(12, 6, BATCH), 256, 0, stream>>>(x, tok_i, outf);
}

// Round 4
// 108.691 us; speedup vs baseline: 1.4106x; 1.4106x over previous
//
#include <hip/hip_runtime.h>

#define BATCH 128
#define CH    768
#define HW    576      // 24*24
#define NTOK  144      // 12*12 tokens
#define NMERGE 72
#define NKEEP 360      // 72*1 + 72*4 output tokens
#define CCH   16       // channels per score chunk
#define NCH   48       // score chunks (768/16)
#define GC    32       // channels per gather block

// ---------------------------------------------------------------------------
// Kernel 1: per-(b, chunk, token-pair) partial scores. No LDS, no syncs.
// Thread owns 2 adjacent tokens; two float4 loads per channel cover the
// even row (both anchors + right pixels) and the full odd row. Fully
// coalesced; x is read exactly once. Deterministic fixed-order summation.
// ---------------------------------------------------------------------------
__global__ __launch_bounds__(256) void score_kernel(const float* __restrict__ x,
                                                    float* __restrict__ part) {
    int w  = blockIdx.x * 256 + threadIdx.x;     // 128*48*72 work items, no tail
    int b  = w / (NCH * 72);
    int r  = w - b * (NCH * 72);
    int ch = r / 72;
    int tp = r - ch * 72;
    int i  = tp / 6, jp = tp - i * 6;            // token row, token-pair col
    const float* xb = x + ((size_t)b * CH + (size_t)ch * CCH) * HW + i * 48 + jp * 4;
    float acc0 = 0.f, acc1 = 0.f;
#pragma unroll
    for (int cc = 0; cc < CCH; ++cc) {
        float4 v0 = *(const float4*)(xb + (size_t)cc * HW);        // even row
        float4 v1 = *(const float4*)(xb + (size_t)cc * HW + 24);   // odd row
        acc0 += fabsf(v0.y - v0.x) + fabsf(v1.x - v0.x) + fabsf(v1.y - v0.x);
        acc1 += fabsf(v0.w - v0.z) + fabsf(v1.z - v0.z) + fabsf(v1.w - v0.z);
    }
    int t0 = i * 12 + jp * 2;
    *(float2*)(part + ((size_t)b * NCH + ch) * NTOK + t0) = make_float2(acc0, acc1);
}

// ---------------------------------------------------------------------------
// Kernel 2: per-batch. Reduce partials -> scores, rank (stable), build the
// per-pixel include mask, prefix-sum via ballot/popcount, emit token_idx
// (float into d_out tail, int into ws for the gather). 576 thr = 9 waves.
// ---------------------------------------------------------------------------
__global__ __launch_bounds__(576) void select_kernel(const float* __restrict__ part,
                                                     float* __restrict__ tok_f,
                                                     int* __restrict__ tok_i) {
    int b = blockIdx.x;
    int tid = threadIdx.x;
    __shared__ float s[NTOK];
    __shared__ int   merged[NTOK];
    __shared__ unsigned long long wmask[9];

    if (tid < NTOK) {
        float v = 0.f;
        for (int ch = 0; ch < NCH; ++ch)
            v += part[((size_t)b * NCH + ch) * NTOK + tid];
        s[tid] = v;
    }
    __syncthreads();
    if (tid < NTOK) {
        float v = s[tid];
        int rank = 0;
        for (int u = 0; u < NTOK; ++u) {
            float su = s[u];
            rank += (su < v) || (su == v && u < tid);   // stable argsort rank
        }
        merged[tid] = (rank < NMERGE);
    }
    __syncthreads();

    // tid = pixel p in [0,576)
    int row = tid / 24, col = tid % 24;
    int t = (row >> 1) * 12 + (col >> 1);
    bool inc = merged[t] ? ((row & 1) == 0 && (col & 1) == 0) : true;
    unsigned long long mask = __ballot(inc);
    int wv = tid >> 6, lane = tid & 63;
    if (lane == 0) wmask[wv] = mask;
    __syncthreads();
    int pos = 0;
    for (int w = 0; w < wv; ++w) pos += __popcll(wmask[w]);
    pos += __popcll(mask & ((1ULL << lane) - 1ULL));
    if (inc) {
        tok_f[(size_t)b * NKEEP + pos] = (float)tid;  // output 1 (as float)
        tok_i[(size_t)b * NKEEP + pos] = tid;         // for gather kernel
    }
}

// ---------------------------------------------------------------------------
// Kernel 3: gather + transpose via full-row LDS staging. Block = (b, 32-ch
// tile). Stage 32 full 576-float rows coalesced (float4), pad 577 so the
// gather read bank = (c+p)%32 is conflict-free; write out[b,k,c] coalesced.
// ---------------------------------------------------------------------------
__global__ __launch_bounds__(256) void gather_kernel(const float* __restrict__ x,
                                                     const int* __restrict__ tok_i,
                                                     float* __restrict__ out) {
    __shared__ float lds[GC * 577];        // [c][p], pad 577
    __shared__ int tok[NKEEP];
    int b = blockIdx.y, ct = blockIdx.x;   // 24 channel tiles
    int tid = threadIdx.x;
    for (int k = tid; k < NKEEP; k += 256) tok[k] = tok_i[(size_t)b * NKEEP + k];
    const float* xb = x + ((size_t)b * CH + (size_t)ct * GC) * HW;
#pragma unroll
    for (int q = 0; q < 18; ++q) {         // 32*144 float4s / 256 threads
        int idx = q * 256 + tid;
        int c = idx / 144, p4 = (idx - c * 144) * 4;
        float4 v = *(const float4*)(xb + (size_t)c * HW + p4);
        float* d = &lds[c * 577 + p4];
        d[0] = v.x; d[1] = v.y; d[2] = v.z; d[3] = v.w;
    }
    __syncthreads();
    int c = tid & 31, kh = tid >> 5;       // 8 k-groups of 45
    float* ob = out + (size_t)b * NKEEP * CH + (size_t)ct * GC + c;
#pragma unroll 5
    for (int it = 0; it < 45; ++it) {
        int k = kh * 45 + it;
        int p = tok[k];
        ob[(size_t)k * CH] = lds[c * 577 + p];
    }
}

extern "C" void kernel_launch(void* const* d_in, const int* in_sizes, int n_in,
                              void* d_out, int out_size, void* d_ws, size_t ws_size,
                              hipStream_t stream) {
    const float* x = (const float*)d_in[0];
    float* outf = (float*)d_out;
    float* part = (float*)d_ws;                                   // 128*48*144 f32
    int* tok_i = (int*)((char*)d_ws + (size_t)BATCH * NCH * NTOK * sizeof(float));
    float* tok_f = outf + (size_t)BATCH * NKEEP * CH;             // token_idx area

    score_kernel<<<dim3(BATCH * NCH * 72 / 256), 256, 0, stream>>>(x, part);
    select_kernel<<<dim3(BATCH), 576, 0, stream>>>(part, tok_f, tok_i);
    gather_kernel<<<dim3(24, BATCH), 256, 0, stream>>>(x, tok_i, outf);
}

// Round 6
// 99.727 us; speedup vs baseline: 1.5373x; 1.0899x over previous
//
#include <hip/hip_runtime.h>

#define BATCH 128
#define CH    768
#define HW    576      // 24*24
#define NTOK  144      // 12*12 tokens
#define NMERGE 72
#define NKEEP 360      // 72*1 + 72*4 output tokens
#define CCH   16       // channels per score chunk
#define NCH   48       // score chunks (768/16)
#define GC    16       // channels per gather block (38.4 KB LDS -> 4 blocks/CU)

// ---------------------------------------------------------------------------
// Kernel 1: per-(b, chunk, token-pair) partial scores. No LDS, no syncs.
// Thread owns 2 adjacent tokens; two float4 loads per channel cover the
// even row (both anchors + right pixels) and the full odd row. Fully
// coalesced; x is read exactly once. Deterministic fixed-order summation.
// ---------------------------------------------------------------------------
__global__ __launch_bounds__(256) void score_kernel(const float* __restrict__ x,
                                                    float* __restrict__ part) {
    int w  = blockIdx.x * 256 + threadIdx.x;     // 128*48*72 work items, no tail
    int b  = w / (NCH * 72);
    int r  = w - b * (NCH * 72);
    int ch = r / 72;
    int tp = r - ch * 72;
    int i  = tp / 6, jp = tp - i * 6;            // token row, token-pair col
    const float* xb = x + ((size_t)b * CH + (size_t)ch * CCH) * HW + i * 48 + jp * 4;
    float acc0 = 0.f, acc1 = 0.f;
#pragma unroll
    for (int cc = 0; cc < CCH; ++cc) {
        float4 v0 = *(const float4*)(xb + (size_t)cc * HW);        // even row
        float4 v1 = *(const float4*)(xb + (size_t)cc * HW + 24);   // odd row
        acc0 += fabsf(v0.y - v0.x) + fabsf(v1.x - v0.x) + fabsf(v1.y - v0.x);
        acc1 += fabsf(v0.w - v0.z) + fabsf(v1.z - v0.z) + fabsf(v1.w - v0.z);
    }
    int t0 = i * 12 + jp * 2;
    *(float2*)(part + ((size_t)b * NCH + ch) * NTOK + t0) = make_float2(acc0, acc1);
}

// ---------------------------------------------------------------------------
// Kernel 2: per-batch. Reduce partials -> scores, rank (stable), build the
// per-pixel include mask, prefix-sum via ballot/popcount, emit token_idx
// (float into d_out tail, int into ws for the gather). 576 thr = 9 waves.
// ---------------------------------------------------------------------------
__global__ __launch_bounds__(576) void select_kernel(const float* __restrict__ part,
                                                     float* __restrict__ tok_f,
                                                     int* __restrict__ tok_i) {
    int b = blockIdx.x;
    int tid = threadIdx.x;
    __shared__ float s[NTOK];
    __shared__ int   merged[NTOK];
    __shared__ unsigned long long wmask[9];

    if (tid < NTOK) {
        float v = 0.f;
        for (int ch = 0; ch < NCH; ++ch)
            v += part[((size_t)b * NCH + ch) * NTOK + tid];
        s[tid] = v;
    }
    __syncthreads();
    if (tid < NTOK) {
        float v = s[tid];
        int rank = 0;
        for (int u = 0; u < NTOK; ++u) {
            float su = s[u];
            rank += (su < v) || (su == v && u < tid);   // stable argsort rank
        }
        merged[tid] = (rank < NMERGE);
    }
    __syncthreads();

    // tid = pixel p in [0,576)
    int row = tid / 24, col = tid % 24;
    int t = (row >> 1) * 12 + (col >> 1);
    bool inc = merged[t] ? ((row & 1) == 0 && (col & 1) == 0) : true;
    unsigned long long mask = __ballot(inc);
    int wv = tid >> 6, lane = tid & 63;
    if (lane == 0) wmask[wv] = mask;
    __syncthreads();
    int pos = 0;
    for (int w = 0; w < wv; ++w) pos += __popcll(wmask[w]);
    pos += __popcll(mask & ((1ULL << lane) - 1ULL));
    if (inc) {
        tok_f[(size_t)b * NKEEP + pos] = (float)tid;  // output 1 (as float)
        tok_i[(size_t)b * NKEEP + pos] = tid;         // for gather kernel
    }
}

// ---------------------------------------------------------------------------
// Kernel 3: gather + transpose via full-row LDS staging. Block = (b, 16-ch
// tile). Stage 16 full 576-float rows coalesced (float4), pad 577 so the
// gather read bank = (c+p)%32 spans 16 consecutive banks per p-group
// (<=4-way worst case, ~2-way typical). Nontemporal coalesced writes keep
// the streamed output from evicting x out of L3 (x should be L3-resident
// from the score pass -> staging reads mostly L3 hits).
// ---------------------------------------------------------------------------
__global__ __launch_bounds__(256) void gather_kernel(const float* __restrict__ x,
                                                     const int* __restrict__ tok_i,
                                                     float* __restrict__ out) {
    __shared__ float lds[GC * 577];        // [c][p], pad 577 (36.9 KB)
    __shared__ int tok[NKEEP];
    int b = blockIdx.y, ct = blockIdx.x;   // 48 channel tiles
    int tid = threadIdx.x;
    for (int k = tid; k < NKEEP; k += 256) tok[k] = tok_i[(size_t)b * NKEEP + k];
    const float* xb = x + ((size_t)b * CH + (size_t)ct * GC) * HW;
#pragma unroll
    for (int q = 0; q < 9; ++q) {          // 16*144 float4s / 256 threads
        int idx = q * 256 + tid;
        int c = idx / 144, p4 = (idx - c * 144) * 4;
        float4 v = *(const float4*)(xb + (size_t)c * HW + p4);
        float* d = &lds[c * 577 + p4];
        d[0] = v.x; d[1] = v.y; d[2] = v.z; d[3] = v.w;
    }
    __syncthreads();
    int c = tid & 15, kh = tid >> 4;       // 16 k-groups
    float* ob = out + (size_t)b * NKEEP * CH + (size_t)ct * GC + c;
#pragma unroll
    for (int it = 0; it < 23; ++it) {
        int k = it * 16 + kh;              // last iter masked (352..367 vs 360)
        if (k < NKEEP)
            __builtin_nontemporal_store(lds[c * 577 + tok[k]], ob + (size_t)k * CH);
    }
}

extern "C" void kernel_launch(void* const* d_in, const int* in_sizes, int n_in,
                              void* d_out, int out_size, void* d_ws, size_t ws_size,
                              hipStream_t stream) {
    const float* x = (const float*)d_in[0];
    float* outf = (float*)d_out;
    float* part = (float*)d_ws;                                   // 128*48*144 f32
    int* tok_i = (int*)((char*)d_ws + (size_t)BATCH * NCH * NTOK * sizeof(float));
    float* tok_f = outf + (size_t)BATCH * NKEEP * CH;             // token_idx area

    score_kernel<<<dim3(BATCH * NCH * 72 / 256), 256, 0, stream>>>(x, part);
    select_kernel<<<dim3(BATCH), 576, 0, stream>>>(part, tok_f, tok_i);
    gather_kernel<<<dim3(48, BATCH), 256, 0, stream>>>(x, tok_i, outf);
}